// Round 12
// baseline (433.113 us; speedup 1.0000x reference)
//
#include <hip/hip_runtime.h>
#include <hip/hip_bf16.h>
#include <hip/hip_fp16.h>

#define N_NODES 100000
#define N_EDGES 3200000
#define NBUCK 782          // ceil(100000/128) buckets of 128 nodes
#define P1_CHUNK 6144      // edges per p1b block (= 24 * 256)
#define BCAP 4800          // fixed region per bucket (mean 4092, sd ~64 -> 11 sigma)

typedef _Float16 half4f __attribute__((ext_vector_type(4)));
typedef float floatx4 __attribute__((ext_vector_type(4)));

__device__ __forceinline__ float f4c(const float4& v, int k) {
    switch (k & 3) { case 0: return v.x; case 1: return v.y; case 2: return v.z; default: return v.w; }
}
__device__ __forceinline__ void fma4(float4& a, float s, const float4& w) {
    a.x += s * w.x; a.y += s * w.y; a.z += s * w.z; a.w += s * w.w;
}

// ---------------- CSR build (fixed-capacity bucket sort, coalesced writes) ----------------

__global__ __launch_bounds__(256) void init_cursor(int* __restrict__ cursor) {
    int i = blockIdx.x * 256 + threadIdx.x;
    if (i < NBUCK) cursor[i] = i * BCAP;
}

// scatter packed (local<<17|src) into fixed bucket regions of tmp, LDS-staged
// dst values register-cached across the two passes (24 compile-time-indexed regs)
__global__ __launch_bounds__(256) void p1b_scatter(const int* __restrict__ src, const int* __restrict__ dst,
                                                   int* __restrict__ bucket_cursor, unsigned* __restrict__ tmp) {
    __shared__ unsigned stage[P1_CHUNK];        // 24 KB
    __shared__ unsigned short stageb[P1_CHUNK]; // 12 KB
    __shared__ int lhist[NBUCK];
    __shared__ int lbase[NBUCK];
    __shared__ int gbase[NBUCK];
    __shared__ int wpart[4];
    const int tid = threadIdx.x;
    const int lane = tid & 63;
    const int wid = tid >> 6;
    const long e0 = (long)blockIdx.x * P1_CHUNK;
    const int nvalid = (int)min((long)P1_CHUNK, (long)N_EDGES - e0);
    for (int i = tid; i < NBUCK; i += 256) lhist[i] = 0;
    __syncthreads();
    int myd[24];
#pragma unroll
    for (int k = 0; k < 24; ++k) {
        int i = tid + k * 256;
        int d = (i < nvalid) ? __builtin_nontemporal_load(&dst[e0 + i]) : -1;
        myd[k] = d;
        if (d >= 0) atomicAdd(&lhist[d >> 7], 1);
    }
    __syncthreads();
    int c[4];
    const int idx0 = tid * 4;
    int tsum = 0;
#pragma unroll
    for (int i = 0; i < 4; ++i) {
        int id = idx0 + i;
        c[i] = (id < NBUCK) ? lhist[id] : 0;
        tsum += c[i];
    }
    int incl = tsum;
#pragma unroll
    for (int off = 1; off < 64; off <<= 1) {
        int t = __shfl_up(incl, (unsigned)off, 64);
        if (lane >= off) incl += t;
    }
    if (lane == 63) wpart[wid] = incl;
    __syncthreads();
    int wpre = 0;
#pragma unroll
    for (int w = 0; w < 4; ++w) { if (w < wid) wpre += wpart[w]; }
    int run = wpre + incl - tsum;
#pragma unroll
    for (int i = 0; i < 4; ++i) {
        int id = idx0 + i;
        if (id < NBUCK) { lbase[id] = run; run += c[i]; }
    }
    __syncthreads();
    for (int i = tid; i < NBUCK; i += 256) {
        int cnt = lhist[i];
        gbase[i] = (cnt > 0) ? atomicAdd(&bucket_cursor[i], cnt) : 0;
    }
    __syncthreads();
    for (int i = tid; i < NBUCK; i += 256) lhist[i] = 0;
    __syncthreads();
#pragma unroll
    for (int k = 0; k < 24; ++k) {
        int i = tid + k * 256;
        int d = myd[k];
        if (d >= 0) {
            int s = __builtin_nontemporal_load(&src[e0 + i]);
            int b = d >> 7;
            int r = atomicAdd(&lhist[b], 1);
            int pos = lbase[b] + r;
            stage[pos] = ((unsigned)(d & 127) << 17) | (unsigned)s;
            stageb[pos] = (unsigned short)b;
        }
    }
    __syncthreads();
    for (int i = tid; i < nvalid; i += 256) {
        unsigned p = stage[i];
        int b = stageb[i];
        long gp = (long)gbase[b] + (i - lbase[b]);
        __builtin_nontemporal_store(p, &tmp[gp]);
    }
}

// per-bucket counting sort in LDS -> s_src (padded layout); emits row_start/row_end and dis
__global__ __launch_bounds__(256) void p2_sort(const unsigned* __restrict__ tmp, const int* __restrict__ bucket_cursor,
                                               int* __restrict__ s_src, int* __restrict__ row_start,
                                               int* __restrict__ row_end, float* __restrict__ dis) {
    __shared__ unsigned pk[BCAP];   // 19.2 KB
    __shared__ int sorted[BCAP];    // 19.2 KB
    __shared__ int cnt128[128];
    __shared__ int pref[129];
    __shared__ int w2[2];
    const int b = blockIdx.x;
    const int tid = threadIdx.x;
    const int lane = tid & 63;
    const int base = b * BCAP;
    int cnt = bucket_cursor[b] - base;
    if (cnt > BCAP) cnt = BCAP;
    const int nbase = b << 7;
    for (int i = tid; i < 128; i += 256) cnt128[i] = 0;
    __syncthreads();
    for (int i = tid; i < cnt; i += 256) {
        unsigned p = __builtin_nontemporal_load(&tmp[base + i]);
        pk[i] = p;
        atomicAdd(&cnt128[p >> 17], 1);
    }
    __syncthreads();
    int v = (tid < 128) ? cnt128[tid] : 0;
    int incl = v;
#pragma unroll
    for (int off = 1; off < 64; off <<= 1) {
        int t = __shfl_up(incl, (unsigned)off, 64);
        if (lane >= off) incl += t;
    }
    if (tid < 128 && lane == 63) w2[tid >> 6] = incl;
    __syncthreads();
    if (tid < 128 && (tid >> 6) == 1) incl += w2[0];
    if (tid < 128) { pref[tid + 1] = incl; if (tid == 0) pref[0] = 0; }
    __syncthreads();
    const int nnodes = min(128, N_NODES - nbase);
    if (tid < nnodes) {
        const int c0 = cnt128[tid];
        row_start[nbase + tid] = base + pref[tid];
        row_end[nbase + tid] = base + pref[tid] + c0;
        dis[nbase + tid] = rsqrtf((float)c0 + 1.0f);
    }
    if (tid < 128) cnt128[tid] = pref[tid];
    __syncthreads();
    for (int i = tid; i < cnt; i += 256) {
        unsigned p = pk[i];
        int l = p >> 17;
        int pos = atomicAdd(&cnt128[l], 1);
        sorted[pos] = (int)(p & 0x1FFFFu);
    }
    __syncthreads();
    for (int i = tid; i < cnt; i += 256)
        __builtin_nontemporal_store(sorted[i], &s_src[base + i]);
}

// ---------------- dense lin with fused dis pre-scale, fp16 out ----------------
// fp32 input variant (conv1); x is stream-once -> nt loads (via ext-vector float4)
template <int K, int O>
__global__ __launch_bounds__(256) void lin_h_kernel(const float* __restrict__ X, const float* __restrict__ W,
                                                    const float* __restrict__ dis, __half* __restrict__ Y) {
    __shared__ float4 Wl[K * O / 4];
    const int tid = threadIdx.x;
    for (int i = tid; i < K * O / 4; i += 256) Wl[i] = reinterpret_cast<const float4*>(W)[i];
    __syncthreads();
    const int node = blockIdx.x * 256 + tid;
    if (node >= N_NODES) return;
    float4 acc[O / 4];
#pragma unroll
    for (int j = 0; j < O / 4; ++j) acc[j] = make_float4(0.f, 0.f, 0.f, 0.f);
    const floatx4* Xr = reinterpret_cast<const floatx4*>(X + (size_t)node * K);
#pragma unroll 2
    for (int k4 = 0; k4 < K / 4; ++k4) {
        floatx4 xv = __builtin_nontemporal_load(&Xr[k4]);
#pragma unroll
        for (int kk = 0; kk < 4; ++kk) {
            float xs = xv[kk];
#pragma unroll
            for (int j = 0; j < O / 4; ++j) fma4(acc[j], xs, Wl[(k4 * 4 + kk) * (O / 4) + j]);
        }
    }
    const float s = dis[node];
    union { uint4 u[O / 8]; __half2 h[O / 2]; } pk;
#pragma unroll
    for (int j = 0; j < O / 4; ++j) {
        pk.h[2 * j]     = __floats2half2_rn(acc[j].x * s, acc[j].y * s);
        pk.h[2 * j + 1] = __floats2half2_rn(acc[j].z * s, acc[j].w * s);
    }
    uint4* Yr = reinterpret_cast<uint4*>(Y + (size_t)node * O);
#pragma unroll
    for (int j = 0; j < O / 8; ++j) Yr[j] = pk.u[j];
}

// fp16 input variant (conv2/conv3)
template <int K, int O>
__global__ __launch_bounds__(256) void lin_h16_kernel(const __half* __restrict__ X, const float* __restrict__ W,
                                                      const float* __restrict__ dis, __half* __restrict__ Y) {
    __shared__ float4 Wl[K * O / 4];
    const int tid = threadIdx.x;
    for (int i = tid; i < K * O / 4; i += 256) Wl[i] = reinterpret_cast<const float4*>(W)[i];
    __syncthreads();
    const int node = blockIdx.x * 256 + tid;
    if (node >= N_NODES) return;
    float4 acc[O / 4];
#pragma unroll
    for (int j = 0; j < O / 4; ++j) acc[j] = make_float4(0.f, 0.f, 0.f, 0.f);
    const uint4* Xr = reinterpret_cast<const uint4*>(X + (size_t)node * K);
#pragma unroll 2
    for (int k8 = 0; k8 < K / 8; ++k8) {
        uint4 xv = Xr[k8];
        const __half2* h = reinterpret_cast<const __half2*>(&xv);
#pragma unroll
        for (int p = 0; p < 4; ++p) {
            float2 f = __half22float2(h[p]);
#pragma unroll
            for (int j = 0; j < O / 4; ++j) {
                fma4(acc[j], f.x, Wl[(k8 * 8 + 2 * p) * (O / 4) + j]);
                fma4(acc[j], f.y, Wl[(k8 * 8 + 2 * p + 1) * (O / 4) + j]);
            }
        }
    }
    const float s = dis[node];
    union { uint4 u[O / 8]; __half2 h[O / 2]; } pk;
#pragma unroll
    for (int j = 0; j < O / 4; ++j) {
        pk.h[2 * j]     = __floats2half2_rn(acc[j].x * s, acc[j].y * s);
        pk.h[2 * j + 1] = __floats2half2_rn(acc[j].z * s, acc[j].w * s);
    }
    uint4* Yr = reinterpret_cast<uint4*>(Y + (size_t)node * O);
#pragma unroll
    for (int j = 0; j < O / 8; ++j) Yr[j] = pk.u[j];
}

// ---------------- aggregation: 8 nodes/wave, 8 lanes/node, 16B/lane gathers ----------------
// fp16 add-tree per 8-edge batch; s_src is stream-once -> nt loads keep L2 for Hp.

__device__ __forceinline__ void acc8(float* acc, const uint4& v) {
    const __half2* h = reinterpret_cast<const __half2*>(&v);
#pragma unroll
    for (int i = 0; i < 4; ++i) {
        float2 f = __half22float2(h[i]);
        acc[2 * i] += f.x; acc[2 * i + 1] += f.y;
    }
}

__device__ __forceinline__ void hadd4(uint4& a, const uint4& b) {
    __half2* ha = reinterpret_cast<__half2*>(&a);
    const __half2* hb = reinterpret_cast<const __half2*>(&b);
#pragma unroll
    for (int i = 0; i < 4; ++i) ha[i] = __hadd2(ha[i], hb[i]);
}

template <bool RELU, bool RESIDUAL>
__global__ __launch_bounds__(256) void agg64_kernel(const __half* __restrict__ Hp, __half* __restrict__ Yh,
                                                    const float* __restrict__ dis,
                                                    const int* __restrict__ row_start,
                                                    const int* __restrict__ row_end,
                                                    const int* __restrict__ s_src,
                                                    const float* __restrict__ bias) {
    const int tid = threadIdx.x;
    const int lane = tid & 63;
    const int grp = lane >> 3;   // node group 0..7
    const int sub = lane & 7;    // feature slot (8 fp16 each)
    const int node = (blockIdx.x * 4 + (tid >> 6)) * 8 + grp;
    float acc[8];
    {
        uint4 self = *reinterpret_cast<const uint4*>(Hp + (size_t)node * 64 + sub * 8);
        const __half2* h = reinterpret_cast<const __half2*>(&self);
#pragma unroll
        for (int i = 0; i < 4; ++i) {
            float2 f = __half22float2(h[i]);
            acc[2 * i] = f.x; acc[2 * i + 1] = f.y;
        }
    }
    const int rs = row_start[node], re = row_end[node];
    const int nb = (re - rs) >> 3;    // full 8-edge batches
    int e = rs;
    int idx = (nb > 0) ? __builtin_nontemporal_load(&s_src[e + sub]) : 0;
    for (int b = 0; b < nb; ++b) {
        int idx_next = (b + 1 < nb) ? __builtin_nontemporal_load(&s_src[e + 8 + sub]) : 0;
        uint4 v[8];
#pragma unroll
        for (int k = 0; k < 8; ++k) {
            int s = __shfl(idx, (grp << 3) | k, 64);
            v[k] = *reinterpret_cast<const uint4*>(Hp + (size_t)s * 64 + sub * 8);
        }
        hadd4(v[0], v[1]); hadd4(v[2], v[3]); hadd4(v[4], v[5]); hadd4(v[6], v[7]);
        hadd4(v[0], v[2]); hadd4(v[4], v[6]);
        hadd4(v[0], v[4]);
        acc8(acc, v[0]);
        idx = idx_next;
        e += 8;
    }
    for (; e < re; ++e) {
        int s = __builtin_nontemporal_load(&s_src[e]);
        uint4 v = *reinterpret_cast<const uint4*>(Hp + (size_t)s * 64 + sub * 8);
        acc8(acc, v);
    }
    const float di = dis[node];
    const float4* bp = reinterpret_cast<const float4*>(bias + sub * 8);
    float4 b0 = bp[0], b1 = bp[1];
    float out[8];
#pragma unroll
    for (int i = 0; i < 4; ++i) out[i] = acc[i] * di + f4c(b0, i);
#pragma unroll
    for (int i = 0; i < 4; ++i) out[4 + i] = acc[4 + i] * di + f4c(b1, i);
    if (RELU) {
#pragma unroll
        for (int i = 0; i < 8; ++i) out[i] = fmaxf(out[i], 0.0f);
    }
    uint4* Yr = reinterpret_cast<uint4*>(Yh + (size_t)node * 64 + sub * 8);
    if (RESIDUAL) {
        uint4 rv = *Yr;
        const __half2* h = reinterpret_cast<const __half2*>(&rv);
#pragma unroll
        for (int i = 0; i < 4; ++i) {
            float2 f = __half22float2(h[i]);
            out[2 * i] += f.x; out[2 * i + 1] += f.y;
        }
    }
    union { uint4 u; __half2 h[4]; } pkout;
#pragma unroll
    for (int i = 0; i < 4; ++i) pkout.h[i] = __floats2half2_rn(out[2 * i], out[2 * i + 1]);
    *Yr = pkout.u;
}

// one wave per node, 4 edge-subgroups x 16 features
__global__ __launch_bounds__(256) void agg16_kernel(const __half* __restrict__ Hp, __half* __restrict__ H3,
                                                    const float* __restrict__ dis,
                                                    const int* __restrict__ row_start,
                                                    const int* __restrict__ row_end,
                                                    const int* __restrict__ s_src,
                                                    const float* __restrict__ bias) {
    const int tid = threadIdx.x;
    const int lane = tid & 63;
    const int wid = tid >> 6;
    const int node = blockIdx.x * 4 + wid;
    if (node >= N_NODES) return;
    const int j = lane & 15;
    const int es = lane >> 4;
    float acc = (es == 0) ? __half2float(Hp[(size_t)node * 16 + j]) : 0.0f;
    const int rs = row_start[node], re = row_end[node];
    int e = rs + es;
    for (; e + 4 < re; e += 8) {
        int s0 = s_src[e];
        int s1 = s_src[e + 4];
        float h0 = __half2float(Hp[(size_t)s0 * 16 + j]);
        float h1 = __half2float(Hp[(size_t)s1 * 16 + j]);
        acc += h0 + h1;
    }
    if (e < re) acc += __half2float(Hp[(size_t)s_src[e] * 16 + j]);
    acc += __shfl_xor(acc, 16, 64);
    acc += __shfl_xor(acc, 32, 64);
    if (es == 0) {
        float out = acc * dis[node] + bias[j];
        H3[(size_t)node * 16 + j] = __float2half_rn(out);
    }
}

// ---------------- edge MLP + log_softmax: MFMA, weights in registers, 4-deep ----------------
// nt loads on src/dst (stream-once) and nt stores on out (write-once, 204.8MB) keep
// the 3.2MB H3 gather table resident in each XCD's L2.

__global__ __launch_bounds__(256) void edge_mlp_kernel(const __half* __restrict__ H3,
                                                       const int* __restrict__ src, const int* __restrict__ dst,
                                                       const float* __restrict__ fc1W, const float* __restrict__ fc1b,
                                                       const float* __restrict__ fc2W, const float* __restrict__ fc2b,
                                                       float* __restrict__ out) {
    const int lane = threadIdx.x & 63;
    const int g = lane >> 4;       // lane group 0..3
    const int c = lane & 15;       // edge-slot / weight column
    half4f a1a, a1b, a2;
    floatx4 cb1, cb2;
#pragma unroll
    for (int j = 0; j < 4; ++j) {
        a1a[j] = (_Float16)fc1W[(4 * g + j) * 16 + c];
        a1b[j] = (_Float16)fc1W[(16 + 4 * g + j) * 16 + c];
        a2[j]  = (_Float16)fc2W[(4 * g + j) * 16 + c];
        cb1[j] = fc1b[4 * g + j];
        cb2[j] = fc2b[4 * g + j];
    }
    const int wave_id = blockIdx.x * 4 + ((int)threadIdx.x >> 6);
    const int nwaves = gridDim.x * 4;
    for (long eb = (long)wave_id * 64; eb < N_EDGES; eb += (long)nwaves * 64) {
        int e[4], si[4], di[4];
#pragma unroll
        for (int t = 0; t < 4; ++t) e[t] = (int)eb + 16 * t + c;
#pragma unroll
        for (int t = 0; t < 4; ++t) {
            si[t] = __builtin_nontemporal_load(&src[e[t]]);
            di[t] = __builtin_nontemporal_load(&dst[e[t]]);
        }
        half4f bs[4], bd[4];
#pragma unroll
        for (int t = 0; t < 4; ++t) {
            bs[t] = *reinterpret_cast<const half4f*>(H3 + (size_t)si[t] * 16 + 4 * g);
            bd[t] = *reinterpret_cast<const half4f*>(H3 + (size_t)di[t] * 16 + 4 * g);
        }
        floatx4 o[4];
#pragma unroll
        for (int t = 0; t < 4; ++t) {
            floatx4 tt = cb1;
            tt = __builtin_amdgcn_mfma_f32_16x16x16f16(a1a, bs[t], tt, 0, 0, 0);
            tt = __builtin_amdgcn_mfma_f32_16x16x16f16(a1b, bd[t], tt, 0, 0, 0);
            half4f tb;
#pragma unroll
            for (int i = 0; i < 4; ++i) tb[i] = (_Float16)fmaxf(tt[i], 0.0f);
            o[t] = __builtin_amdgcn_mfma_f32_16x16x16f16(a2, tb, cb2, 0, 0, 0);
        }
#pragma unroll
        for (int t = 0; t < 4; ++t) {
            float m = fmaxf(fmaxf(o[t][0], o[t][1]), fmaxf(o[t][2], o[t][3]));
            m = fmaxf(m, __shfl_xor(m, 16, 64));
            m = fmaxf(m, __shfl_xor(m, 32, 64));
            float su = __expf(o[t][0] - m) + __expf(o[t][1] - m) + __expf(o[t][2] - m) + __expf(o[t][3] - m);
            su += __shfl_xor(su, 16, 64);
            su += __shfl_xor(su, 32, 64);
            const float ls = m + __logf(su);
            floatx4 r;
#pragma unroll
            for (int i = 0; i < 4; ++i) r[i] = o[t][i] - ls;
            __builtin_nontemporal_store(r, reinterpret_cast<floatx4*>(out + (size_t)e[t] * 16 + 4 * g));
        }
    }
}

// ---------------- launch ----------------

extern "C" void kernel_launch(void* const* d_in, const int* in_sizes, int n_in,
                              void* d_out, int out_size, void* d_ws, size_t ws_size,
                              hipStream_t stream) {
    (void)in_sizes; (void)n_in; (void)out_size; (void)ws_size;
    const float* x    = (const float*)d_in[0];
    const int* eidx   = (const int*)d_in[1];
    const float* W1   = (const float*)d_in[2];
    const float* b1   = (const float*)d_in[3];
    const float* W2   = (const float*)d_in[4];
    const float* b2   = (const float*)d_in[5];
    const float* W3   = (const float*)d_in[6];
    const float* b3   = (const float*)d_in[7];
    const float* fc1W = (const float*)d_in[8];
    const float* fc1b = (const float*)d_in[9];
    const float* fc2W = (const float*)d_in[10];
    const float* fc2b = (const float*)d_in[11];
    const int* src = eidx;
    const int* dst = eidx + N_EDGES;

    char* ws = (char*)d_ws;
    size_t off = 0;
    auto alloc = [&](size_t bytes) { size_t cur = off; off = (cur + bytes + 255) & ~(size_t)255; return cur; };
    int*   cursor        = (int*)(ws + alloc((size_t)NBUCK * 4));
    int*   row_start     = (int*)(ws + alloc((size_t)N_NODES * 4));
    int*   row_end       = (int*)(ws + alloc((size_t)N_NODES * 4));
    float* dis           = (float*)(ws + alloc((size_t)N_NODES * 4));
    int*   s_src         = (int*)(ws + alloc((size_t)NBUCK * BCAP * 4));   // padded 15MB
    unsigned* tmp        = (unsigned*)(ws + alloc((size_t)NBUCK * BCAP * 4)); // padded 15MB
    __half* A            = (__half*)(ws + alloc((size_t)N_NODES * 64 * 2)); // fp16 lin out
    __half* Bh           = (__half*)(ws + alloc((size_t)N_NODES * 64 * 2)); // fp16 h1/h2
    __half* H3           = (__half*)(ws + alloc((size_t)N_NODES * 16 * 2)); // fp16 h3
    float* outp          = (float*)d_out;

    const int nblkN = (N_NODES + 255) / 256;
    const int nblkA64 = (N_NODES + 31) / 32;   // 8 nodes/wave * 4 waves
    const int nblkA16 = (N_NODES + 3) / 4;

    // CSR build (fixed-capacity buckets)
    init_cursor<<<(NBUCK + 255) / 256, 256, 0, stream>>>(cursor);
    p1b_scatter<<<(N_EDGES + P1_CHUNK - 1) / P1_CHUNK, 256, 0, stream>>>(src, dst, cursor, tmp);
    p2_sort<<<NBUCK, 256, 0, stream>>>(tmp, cursor, s_src, row_start, row_end, dis);

    // conv1: A = (x@W1)*dis ; Bh = relu(agg(A)*di + b1)
    lin_h_kernel<128, 64><<<nblkN, 256, 0, stream>>>(x, W1, dis, A);
    agg64_kernel<true, false><<<nblkA64, 256, 0, stream>>>(A, Bh, dis, row_start, row_end, s_src, b1);
    // conv2: A = (Bh@W2)*dis ; Bh = relu(agg(A)*di + b2) + Bh
    lin_h16_kernel<64, 64><<<nblkN, 256, 0, stream>>>(Bh, W2, dis, A);
    agg64_kernel<true, true><<<nblkA64, 256, 0, stream>>>(A, Bh, dis, row_start, row_end, s_src, b2);
    // conv3: A16 = (Bh@W3)*dis ; H3 = agg(A16)*di + b3
    lin_h16_kernel<64, 16><<<nblkN, 256, 0, stream>>>(Bh, W3, dis, A);
    agg16_kernel<<<nblkA16, 256, 0, stream>>>(A, H3, dis, row_start, row_end, s_src, b3);
    // edge MLP + log_softmax (MFMA, 4-deep, nt cache policy)
    edge_mlp_kernel<<<2048, 256, 0, stream>>>(H3, src, dst, fc1W, fc1b, fc2W, fc2b, outp);
}

// Round 13
// 364.842 us; speedup vs baseline: 1.1871x; 1.1871x over previous
//
#include <hip/hip_runtime.h>
#include <hip/hip_bf16.h>
#include <hip/hip_fp16.h>

#define N_NODES 100000
#define N_EDGES 3200000
#define NBUCK 782          // ceil(100000/128) buckets of 128 nodes
#define P1_CHUNK 6144      // edges per p1b block
#define BCAP 4800          // fixed region per bucket (mean 4092, sd ~64 -> 11 sigma)

typedef _Float16 half4f __attribute__((ext_vector_type(4)));
typedef float floatx4 __attribute__((ext_vector_type(4)));

__device__ __forceinline__ float f4c(const float4& v, int k) {
    switch (k & 3) { case 0: return v.x; case 1: return v.y; case 2: return v.z; default: return v.w; }
}
__device__ __forceinline__ void fma4(float4& a, float s, const float4& w) {
    a.x += s * w.x; a.y += s * w.y; a.z += s * w.z; a.w += s * w.w;
}

// ---------------- CSR build (fixed-capacity bucket sort, coalesced writes) ----------------

__global__ __launch_bounds__(256) void init_cursor(int* __restrict__ cursor) {
    int i = blockIdx.x * 256 + threadIdx.x;
    if (i < NBUCK) cursor[i] = i * BCAP;
}

// scatter packed (local<<17|src) into fixed bucket regions of tmp, LDS-staged
__global__ __launch_bounds__(256) void p1b_scatter(const int* __restrict__ src, const int* __restrict__ dst,
                                                   int* __restrict__ bucket_cursor, unsigned* __restrict__ tmp) {
    __shared__ unsigned stage[P1_CHUNK];        // 24 KB
    __shared__ unsigned short stageb[P1_CHUNK]; // 12 KB
    __shared__ int lhist[NBUCK];
    __shared__ int lbase[NBUCK];
    __shared__ int gbase[NBUCK];
    __shared__ int wpart[4];
    const int tid = threadIdx.x;
    const int lane = tid & 63;
    const int wid = tid >> 6;
    const long e0 = (long)blockIdx.x * P1_CHUNK;
    const int nvalid = (int)min((long)P1_CHUNK, (long)N_EDGES - e0);
    for (int i = tid; i < NBUCK; i += 256) lhist[i] = 0;
    __syncthreads();
    for (int i = tid; i < nvalid; i += 256) {
        atomicAdd(&lhist[dst[e0 + i] >> 7], 1);
    }
    __syncthreads();
    int c[4];
    const int idx0 = tid * 4;
    int tsum = 0;
#pragma unroll
    for (int i = 0; i < 4; ++i) {
        int id = idx0 + i;
        c[i] = (id < NBUCK) ? lhist[id] : 0;
        tsum += c[i];
    }
    int incl = tsum;
#pragma unroll
    for (int off = 1; off < 64; off <<= 1) {
        int t = __shfl_up(incl, (unsigned)off, 64);
        if (lane >= off) incl += t;
    }
    if (lane == 63) wpart[wid] = incl;
    __syncthreads();
    int wpre = 0;
#pragma unroll
    for (int w = 0; w < 4; ++w) { if (w < wid) wpre += wpart[w]; }
    int run = wpre + incl - tsum;
#pragma unroll
    for (int i = 0; i < 4; ++i) {
        int id = idx0 + i;
        if (id < NBUCK) { lbase[id] = run; run += c[i]; }
    }
    __syncthreads();
    for (int i = tid; i < NBUCK; i += 256) {
        int cnt = lhist[i];
        gbase[i] = (cnt > 0) ? atomicAdd(&bucket_cursor[i], cnt) : 0;
    }
    __syncthreads();
    for (int i = tid; i < NBUCK; i += 256) lhist[i] = 0;
    __syncthreads();
    for (int i = tid; i < nvalid; i += 256) {
        int d = dst[e0 + i];
        int s = src[e0 + i];
        int b = d >> 7;
        int r = atomicAdd(&lhist[b], 1);
        int pos = lbase[b] + r;
        stage[pos] = ((unsigned)(d & 127) << 17) | (unsigned)s;
        stageb[pos] = (unsigned short)b;
    }
    __syncthreads();
    for (int i = tid; i < nvalid; i += 256) {
        unsigned p = stage[i];
        int b = stageb[i];
        long gp = (long)gbase[b] + (i - lbase[b]);
        tmp[gp] = p;
    }
}

// per-bucket counting sort in LDS -> s_src (padded layout); emits row_start/row_end and dis
__global__ __launch_bounds__(256) void p2_sort(const unsigned* __restrict__ tmp, const int* __restrict__ bucket_cursor,
                                               int* __restrict__ s_src, int* __restrict__ row_start,
                                               int* __restrict__ row_end, float* __restrict__ dis) {
    __shared__ unsigned pk[BCAP];   // 19.2 KB
    __shared__ int sorted[BCAP];    // 19.2 KB
    __shared__ int cnt128[128];
    __shared__ int pref[129];
    __shared__ int w2[2];
    const int b = blockIdx.x;
    const int tid = threadIdx.x;
    const int lane = tid & 63;
    const int base = b * BCAP;
    int cnt = bucket_cursor[b] - base;
    if (cnt > BCAP) cnt = BCAP;
    const int nbase = b << 7;
    for (int i = tid; i < 128; i += 256) cnt128[i] = 0;
    __syncthreads();
    for (int i = tid; i < cnt; i += 256) {
        unsigned p = tmp[base + i];
        pk[i] = p;
        atomicAdd(&cnt128[p >> 17], 1);
    }
    __syncthreads();
    int v = (tid < 128) ? cnt128[tid] : 0;
    int incl = v;
#pragma unroll
    for (int off = 1; off < 64; off <<= 1) {
        int t = __shfl_up(incl, (unsigned)off, 64);
        if (lane >= off) incl += t;
    }
    if (tid < 128 && lane == 63) w2[tid >> 6] = incl;
    __syncthreads();
    if (tid < 128 && (tid >> 6) == 1) incl += w2[0];
    if (tid < 128) { pref[tid + 1] = incl; if (tid == 0) pref[0] = 0; }
    __syncthreads();
    const int nnodes = min(128, N_NODES - nbase);
    if (tid < nnodes) {
        const int c0 = cnt128[tid];
        row_start[nbase + tid] = base + pref[tid];
        row_end[nbase + tid] = base + pref[tid] + c0;
        dis[nbase + tid] = rsqrtf((float)c0 + 1.0f);
    }
    if (tid < 128) cnt128[tid] = pref[tid];
    __syncthreads();
    for (int i = tid; i < cnt; i += 256) {
        unsigned p = pk[i];
        int l = p >> 17;
        int pos = atomicAdd(&cnt128[l], 1);
        sorted[pos] = (int)(p & 0x1FFFFu);
    }
    __syncthreads();
    for (int i = tid; i < cnt; i += 256) s_src[base + i] = sorted[i];
}

// ---------------- dense lin with fused dis pre-scale, fp16 out ----------------
// fp32 input variant (conv1)
template <int K, int O>
__global__ __launch_bounds__(256) void lin_h_kernel(const float* __restrict__ X, const float* __restrict__ W,
                                                    const float* __restrict__ dis, __half* __restrict__ Y) {
    __shared__ float4 Wl[K * O / 4];
    const int tid = threadIdx.x;
    for (int i = tid; i < K * O / 4; i += 256) Wl[i] = reinterpret_cast<const float4*>(W)[i];
    __syncthreads();
    const int node = blockIdx.x * 256 + tid;
    if (node >= N_NODES) return;
    float4 acc[O / 4];
#pragma unroll
    for (int j = 0; j < O / 4; ++j) acc[j] = make_float4(0.f, 0.f, 0.f, 0.f);
    const float4* Xr = reinterpret_cast<const float4*>(X + (size_t)node * K);
#pragma unroll 2
    for (int k4 = 0; k4 < K / 4; ++k4) {
        float4 xv = Xr[k4];
#pragma unroll
        for (int kk = 0; kk < 4; ++kk) {
            float xs = f4c(xv, kk);
#pragma unroll
            for (int j = 0; j < O / 4; ++j) fma4(acc[j], xs, Wl[(k4 * 4 + kk) * (O / 4) + j]);
        }
    }
    const float s = dis[node];
    union { uint4 u[O / 8]; __half2 h[O / 2]; } pk;
#pragma unroll
    for (int j = 0; j < O / 4; ++j) {
        pk.h[2 * j]     = __floats2half2_rn(acc[j].x * s, acc[j].y * s);
        pk.h[2 * j + 1] = __floats2half2_rn(acc[j].z * s, acc[j].w * s);
    }
    uint4* Yr = reinterpret_cast<uint4*>(Y + (size_t)node * O);
#pragma unroll
    for (int j = 0; j < O / 8; ++j) Yr[j] = pk.u[j];
}

// fp16 input variant (conv2/conv3)
template <int K, int O>
__global__ __launch_bounds__(256) void lin_h16_kernel(const __half* __restrict__ X, const float* __restrict__ W,
                                                      const float* __restrict__ dis, __half* __restrict__ Y) {
    __shared__ float4 Wl[K * O / 4];
    const int tid = threadIdx.x;
    for (int i = tid; i < K * O / 4; i += 256) Wl[i] = reinterpret_cast<const float4*>(W)[i];
    __syncthreads();
    const int node = blockIdx.x * 256 + tid;
    if (node >= N_NODES) return;
    float4 acc[O / 4];
#pragma unroll
    for (int j = 0; j < O / 4; ++j) acc[j] = make_float4(0.f, 0.f, 0.f, 0.f);
    const uint4* Xr = reinterpret_cast<const uint4*>(X + (size_t)node * K);
#pragma unroll 2
    for (int k8 = 0; k8 < K / 8; ++k8) {
        uint4 xv = Xr[k8];
        const __half2* h = reinterpret_cast<const __half2*>(&xv);
#pragma unroll
        for (int p = 0; p < 4; ++p) {
            float2 f = __half22float2(h[p]);
#pragma unroll
            for (int j = 0; j < O / 4; ++j) {
                fma4(acc[j], f.x, Wl[(k8 * 8 + 2 * p) * (O / 4) + j]);
                fma4(acc[j], f.y, Wl[(k8 * 8 + 2 * p + 1) * (O / 4) + j]);
            }
        }
    }
    const float s = dis[node];
    union { uint4 u[O / 8]; __half2 h[O / 2]; } pk;
#pragma unroll
    for (int j = 0; j < O / 4; ++j) {
        pk.h[2 * j]     = __floats2half2_rn(acc[j].x * s, acc[j].y * s);
        pk.h[2 * j + 1] = __floats2half2_rn(acc[j].z * s, acc[j].w * s);
    }
    uint4* Yr = reinterpret_cast<uint4*>(Y + (size_t)node * O);
#pragma unroll
    for (int j = 0; j < O / 8; ++j) Yr[j] = pk.u[j];
}

// ---------------- aggregation: 8 nodes/wave, 8 lanes/node, 16B/lane gathers ----------------
// fp16 add-tree per 8-edge batch (3 levels of __hadd2) -> one cvt+add into fp32 master acc.

__device__ __forceinline__ void acc8(float* acc, const uint4& v) {
    const __half2* h = reinterpret_cast<const __half2*>(&v);
#pragma unroll
    for (int i = 0; i < 4; ++i) {
        float2 f = __half22float2(h[i]);
        acc[2 * i] += f.x; acc[2 * i + 1] += f.y;
    }
}

__device__ __forceinline__ void hadd4(uint4& a, const uint4& b) {
    __half2* ha = reinterpret_cast<__half2*>(&a);
    const __half2* hb = reinterpret_cast<const __half2*>(&b);
#pragma unroll
    for (int i = 0; i < 4; ++i) ha[i] = __hadd2(ha[i], hb[i]);
}

template <bool RELU, bool RESIDUAL>
__global__ __launch_bounds__(256) void agg64_kernel(const __half* __restrict__ Hp, __half* __restrict__ Yh,
                                                    const float* __restrict__ dis,
                                                    const int* __restrict__ row_start,
                                                    const int* __restrict__ row_end,
                                                    const int* __restrict__ s_src,
                                                    const float* __restrict__ bias) {
    const int tid = threadIdx.x;
    const int lane = tid & 63;
    const int grp = lane >> 3;   // node group 0..7
    const int sub = lane & 7;    // feature slot (8 fp16 each)
    const int node = (blockIdx.x * 4 + (tid >> 6)) * 8 + grp;
    float acc[8];
    {
        uint4 self = *reinterpret_cast<const uint4*>(Hp + (size_t)node * 64 + sub * 8);
        const __half2* h = reinterpret_cast<const __half2*>(&self);
#pragma unroll
        for (int i = 0; i < 4; ++i) {
            float2 f = __half22float2(h[i]);
            acc[2 * i] = f.x; acc[2 * i + 1] = f.y;
        }
    }
    const int rs = row_start[node], re = row_end[node];
    const int nb = (re - rs) >> 3;    // full 8-edge batches
    int e = rs;
    int idx = (nb > 0) ? s_src[e + sub] : 0;
    for (int b = 0; b < nb; ++b) {
        int idx_next = (b + 1 < nb) ? s_src[e + 8 + sub] : 0;   // prefetch next batch
        uint4 v[8];
#pragma unroll
        for (int k = 0; k < 8; ++k) {
            int s = __shfl(idx, (grp << 3) | k, 64);
            v[k] = *reinterpret_cast<const uint4*>(Hp + (size_t)s * 64 + sub * 8);
        }
        // 3-level fp16 tree (feature-preserving), then one fp32 accumulate
        hadd4(v[0], v[1]); hadd4(v[2], v[3]); hadd4(v[4], v[5]); hadd4(v[6], v[7]);
        hadd4(v[0], v[2]); hadd4(v[4], v[6]);
        hadd4(v[0], v[4]);
        acc8(acc, v[0]);
        idx = idx_next;
        e += 8;
    }
    for (; e < re; ++e) {
        int s = s_src[e];
        uint4 v = *reinterpret_cast<const uint4*>(Hp + (size_t)s * 64 + sub * 8);
        acc8(acc, v);
    }
    const float di = dis[node];
    const float4* bp = reinterpret_cast<const float4*>(bias + sub * 8);
    float4 b0 = bp[0], b1 = bp[1];
    float out[8];
#pragma unroll
    for (int i = 0; i < 4; ++i) out[i] = acc[i] * di + f4c(b0, i);
#pragma unroll
    for (int i = 0; i < 4; ++i) out[4 + i] = acc[4 + i] * di + f4c(b1, i);
    if (RELU) {
#pragma unroll
        for (int i = 0; i < 8; ++i) out[i] = fmaxf(out[i], 0.0f);
    }
    uint4* Yr = reinterpret_cast<uint4*>(Yh + (size_t)node * 64 + sub * 8);
    if (RESIDUAL) {
        uint4 rv = *Yr;
        const __half2* h = reinterpret_cast<const __half2*>(&rv);
#pragma unroll
        for (int i = 0; i < 4; ++i) {
            float2 f = __half22float2(h[i]);
            out[2 * i] += f.x; out[2 * i + 1] += f.y;
        }
    }
    union { uint4 u; __half2 h[4]; } pkout;
#pragma unroll
    for (int i = 0; i < 4; ++i) pkout.h[i] = __floats2half2_rn(out[2 * i], out[2 * i + 1]);
    *Yr = pkout.u;
}

// one wave per node, 4 edge-subgroups x 16 features
__global__ __launch_bounds__(256) void agg16_kernel(const __half* __restrict__ Hp, __half* __restrict__ H3,
                                                    const float* __restrict__ dis,
                                                    const int* __restrict__ row_start,
                                                    const int* __restrict__ row_end,
                                                    const int* __restrict__ s_src,
                                                    const float* __restrict__ bias) {
    const int tid = threadIdx.x;
    const int lane = tid & 63;
    const int wid = tid >> 6;
    const int node = blockIdx.x * 4 + wid;
    if (node >= N_NODES) return;
    const int j = lane & 15;
    const int es = lane >> 4;
    float acc = (es == 0) ? __half2float(Hp[(size_t)node * 16 + j]) : 0.0f;
    const int rs = row_start[node], re = row_end[node];
    int e = rs + es;
    for (; e + 4 < re; e += 8) {
        int s0 = s_src[e];
        int s1 = s_src[e + 4];
        float h0 = __half2float(Hp[(size_t)s0 * 16 + j]);
        float h1 = __half2float(Hp[(size_t)s1 * 16 + j]);
        acc += h0 + h1;
    }
    if (e < re) acc += __half2float(Hp[(size_t)s_src[e] * 16 + j]);
    acc += __shfl_xor(acc, 16, 64);
    acc += __shfl_xor(acc, 32, 64);
    if (es == 0) {
        float out = acc * dis[node] + bias[j];
        H3[(size_t)node * 16 + j] = __float2half_rn(out);
    }
}

// ---------------- edge MLP + log_softmax: MFMA, weights in registers, 4-deep ----------------

__global__ __launch_bounds__(256) void edge_mlp_kernel(const __half* __restrict__ H3,
                                                       const int* __restrict__ src, const int* __restrict__ dst,
                                                       const float* __restrict__ fc1W, const float* __restrict__ fc1b,
                                                       const float* __restrict__ fc2W, const float* __restrict__ fc2b,
                                                       float* __restrict__ out) {
    const int lane = threadIdx.x & 63;
    const int g = lane >> 4;       // lane group 0..3
    const int c = lane & 15;       // edge-slot / weight column
    half4f a1a, a1b, a2;
    floatx4 cb1, cb2;
#pragma unroll
    for (int j = 0; j < 4; ++j) {
        a1a[j] = (_Float16)fc1W[(4 * g + j) * 16 + c];
        a1b[j] = (_Float16)fc1W[(16 + 4 * g + j) * 16 + c];
        a2[j]  = (_Float16)fc2W[(4 * g + j) * 16 + c];
        cb1[j] = fc1b[4 * g + j];
        cb2[j] = fc2b[4 * g + j];
    }
    const int wave_id = blockIdx.x * 4 + ((int)threadIdx.x >> 6);
    const int nwaves = gridDim.x * 4;
    for (long eb = (long)wave_id * 64; eb < N_EDGES; eb += (long)nwaves * 64) {
        int e[4], si[4], di[4];
#pragma unroll
        for (int t = 0; t < 4; ++t) e[t] = (int)eb + 16 * t + c;
#pragma unroll
        for (int t = 0; t < 4; ++t) { si[t] = src[e[t]]; di[t] = dst[e[t]]; }
        half4f bs[4], bd[4];
#pragma unroll
        for (int t = 0; t < 4; ++t) {
            bs[t] = *reinterpret_cast<const half4f*>(H3 + (size_t)si[t] * 16 + 4 * g);
            bd[t] = *reinterpret_cast<const half4f*>(H3 + (size_t)di[t] * 16 + 4 * g);
        }
        floatx4 o[4];
#pragma unroll
        for (int t = 0; t < 4; ++t) {
            floatx4 tt = cb1;
            tt = __builtin_amdgcn_mfma_f32_16x16x16f16(a1a, bs[t], tt, 0, 0, 0);
            tt = __builtin_amdgcn_mfma_f32_16x16x16f16(a1b, bd[t], tt, 0, 0, 0);
            half4f tb;
#pragma unroll
            for (int i = 0; i < 4; ++i) tb[i] = (_Float16)fmaxf(tt[i], 0.0f);
            o[t] = __builtin_amdgcn_mfma_f32_16x16x16f16(a2, tb, cb2, 0, 0, 0);
        }
#pragma unroll
        for (int t = 0; t < 4; ++t) {
            float m = fmaxf(fmaxf(o[t][0], o[t][1]), fmaxf(o[t][2], o[t][3]));
            m = fmaxf(m, __shfl_xor(m, 16, 64));
            m = fmaxf(m, __shfl_xor(m, 32, 64));
            float su = __expf(o[t][0] - m) + __expf(o[t][1] - m) + __expf(o[t][2] - m) + __expf(o[t][3] - m);
            su += __shfl_xor(su, 16, 64);
            su += __shfl_xor(su, 32, 64);
            const float ls = m + __logf(su);
            floatx4 r;
#pragma unroll
            for (int i = 0; i < 4; ++i) r[i] = o[t][i] - ls;
            *reinterpret_cast<floatx4*>(out + (size_t)e[t] * 16 + 4 * g) = r;
        }
    }
}

// ---------------- launch ----------------

extern "C" void kernel_launch(void* const* d_in, const int* in_sizes, int n_in,
                              void* d_out, int out_size, void* d_ws, size_t ws_size,
                              hipStream_t stream) {
    (void)in_sizes; (void)n_in; (void)out_size; (void)ws_size;
    const float* x    = (const float*)d_in[0];
    const int* eidx   = (const int*)d_in[1];
    const float* W1   = (const float*)d_in[2];
    const float* b1   = (const float*)d_in[3];
    const float* W2   = (const float*)d_in[4];
    const float* b2   = (const float*)d_in[5];
    const float* W3   = (const float*)d_in[6];
    const float* b3   = (const float*)d_in[7];
    const float* fc1W = (const float*)d_in[8];
    const float* fc1b = (const float*)d_in[9];
    const float* fc2W = (const float*)d_in[10];
    const float* fc2b = (const float*)d_in[11];
    const int* src = eidx;
    const int* dst = eidx + N_EDGES;

    char* ws = (char*)d_ws;
    size_t off = 0;
    auto alloc = [&](size_t bytes) { size_t cur = off; off = (cur + bytes + 255) & ~(size_t)255; return cur; };
    int*   cursor        = (int*)(ws + alloc((size_t)NBUCK * 4));
    int*   row_start     = (int*)(ws + alloc((size_t)N_NODES * 4));
    int*   row_end       = (int*)(ws + alloc((size_t)N_NODES * 4));
    float* dis           = (float*)(ws + alloc((size_t)N_NODES * 4));
    int*   s_src         = (int*)(ws + alloc((size_t)NBUCK * BCAP * 4));   // padded 15MB
    unsigned* tmp        = (unsigned*)(ws + alloc((size_t)NBUCK * BCAP * 4)); // padded 15MB
    __half* A            = (__half*)(ws + alloc((size_t)N_NODES * 64 * 2)); // fp16 lin out
    __half* Bh           = (__half*)(ws + alloc((size_t)N_NODES * 64 * 2)); // fp16 h1/h2
    __half* H3           = (__half*)(ws + alloc((size_t)N_NODES * 16 * 2)); // fp16 h3
    float* outp          = (float*)d_out;

    const int nblkN = (N_NODES + 255) / 256;
    const int nblkA64 = (N_NODES + 31) / 32;   // 8 nodes/wave * 4 waves
    const int nblkA16 = (N_NODES + 3) / 4;

    // CSR build (fixed-capacity buckets: no global histogram/scan passes)
    init_cursor<<<(NBUCK + 255) / 256, 256, 0, stream>>>(cursor);
    p1b_scatter<<<(N_EDGES + P1_CHUNK - 1) / P1_CHUNK, 256, 0, stream>>>(src, dst, cursor, tmp);
    p2_sort<<<NBUCK, 256, 0, stream>>>(tmp, cursor, s_src, row_start, row_end, dis);

    // conv1: A = (x@W1)*dis ; Bh = relu(agg(A)*di + b1)
    lin_h_kernel<128, 64><<<nblkN, 256, 0, stream>>>(x, W1, dis, A);
    agg64_kernel<true, false><<<nblkA64, 256, 0, stream>>>(A, Bh, dis, row_start, row_end, s_src, b1);
    // conv2: A = (Bh@W2)*dis ; Bh = relu(agg(A)*di + b2) + Bh
    lin_h16_kernel<64, 64><<<nblkN, 256, 0, stream>>>(Bh, W2, dis, A);
    agg64_kernel<true, true><<<nblkA64, 256, 0, stream>>>(A, Bh, dis, row_start, row_end, s_src, b2);
    // conv3: A16 = (Bh@W3)*dis ; H3 = agg(A16)*di + b3
    lin_h16_kernel<64, 16><<<nblkN, 256, 0, stream>>>(Bh, W3, dis, A);
    agg16_kernel<<<nblkA16, 256, 0, stream>>>(A, H3, dis, row_start, row_end, s_src, b3);
    // edge MLP + log_softmax (MFMA, 4-deep)
    edge_mlp_kernel<<<2048, 256, 0, stream>>>(H3, src, dst, fc1W, fc1b, fc2W, fc2b, outp);
}